// Round 24
// baseline (186.622 us; speedup 1.0000x reference)
//
#include <hip/hip_runtime.h>
#include <math.h>

// ---------------- problem constants ----------------
#define BB    8
#define NLEN  8192          // sequence length (FFT size)
#define CC    512           // channels
#define HH    8             // heads
#define DH    64            // head dim
#define MH    4096          // NLEN/2 (complex FFT size)
#define FREQ  4097          // rfft bins
#define FP    4160          // region-sizing row equivalent (65 tiles * 64)
#define NSEQ  (BB*CC)       // 4096 rows
#define BHSZ  (65*4096)     // uints per (b,h) group: 65 f-tiles x [i=64][f=64]

// spectrum layout: [b][h][ftile][i][f] bf16-pair bins
#define KADDR(k) ((((k) >> 6) << 12) + ((k) & 63))

// scratch: two regions of NSEQ*FP uint
#define REGION_BYTES ((size_t)NSEQ * FP * 4ull)

static __device__ __align__(256) unsigned char g_scratch[2ull * (size_t)NSEQ * FP * 4ull];
// prepped weights: [h][plane(0=w1r,1=w1i,2=w2r,3=w2i)][o][swizzled k-slot] bf16
__device__ unsigned short g_wprep[8 * 4 * 64 * 64];

typedef __attribute__((ext_vector_type(8))) short bf16x8;
typedef __attribute__((ext_vector_type(4))) float f32x4;
typedef __attribute__((ext_vector_type(4))) unsigned u32x4;

__device__ __forceinline__ f32x4 MFMA(bf16x8 a, bf16x8 b, f32x4 c){
  return __builtin_amdgcn_mfma_f32_16x16x32_bf16(a, b, c, 0, 0, 0);
}

__device__ __forceinline__ unsigned short f2bf(float f){   // rne (wprep only)
  unsigned u = __float_as_uint(f);
  return (unsigned short)((u + 0x7fffu + ((u >> 16) & 1u)) >> 16);
}
// truncating bf16 pack: ONE v_perm (takes high halves of a,b)
__device__ __forceinline__ unsigned pack2t(float a, float b){
  return __builtin_amdgcn_perm(__float_as_uint(b), __float_as_uint(a), 0x07060302u);
}
__device__ __forceinline__ float bflo(unsigned u){ return __uint_as_float(u << 16); }
__device__ __forceinline__ float bfhi(unsigned u){ return __uint_as_float(u & 0xffff0000u); }

// cos/sin(2*pi*q/32) for q=0..15
__device__ const float C32C[16] = {
  1.f, 0.98078528f, 0.92387953f, 0.83146961f, 0.70710678f, 0.55557023f,
  0.38268343f, 0.19509032f, 0.f, -0.19509032f, -0.38268343f, -0.55557023f,
  -0.70710678f, -0.83146961f, -0.92387953f, -0.98078528f};
__device__ const float C32S[16] = {
  0.f, 0.19509032f, 0.38268343f, 0.55557023f, 0.70710678f, 0.83146961f,
  0.92387953f, 0.98078528f, 1.f, 0.98078528f, 0.92387953f, 0.83146961f,
  0.70710678f, 0.55557023f, 0.38268343f, 0.19509032f};

// cheap GELU: v * sigmoid(1.702 v)
__device__ __forceinline__ float gelu_fast(float v){
  float e = __builtin_amdgcn_exp2f(-2.4554572f * v);     // exp(-1.702 v)
  return v * __builtin_amdgcn_rcpf(1.0f + e);
}

// ---------------- complex helpers ----------------
__device__ __forceinline__ float2 cadd(float2 a, float2 b){ return make_float2(a.x+b.x, a.y+b.y); }
__device__ __forceinline__ float2 csub(float2 a, float2 b){ return make_float2(a.x-b.x, a.y-b.y); }
__device__ __forceinline__ float2 cmul(float2 a, float2 b){
  return make_float2(fmaf(a.x, b.x, -(a.y*b.y)), fmaf(a.x, b.y, a.y*b.x));
}

// ---------------- weight prep body (called from 8 transpose blocks) ----------------
__device__ __forceinline__ void wprep_body(int h, int t,
                                           const float* __restrict__ w1,
                                           const float* __restrict__ w2){
  #pragma unroll 4
  for (int u = 0; u < 64; ++u){
    int idx = t + 256*u;
    int p = idx >> 12;
    int o = (idx >> 6) & 63;
    int jj = idx & 63;
    int swo = (o ^ (o >> 3)) & 7;
    int s = (((jj >> 3) ^ swo) << 3) | (jj & 7);
    int i;
    if (p < 2){
      i = s;
    } else {
      int ks = s >> 5, g = (s >> 3) & 3, j = s & 7;
      i = (2*ks + (j >> 2))*16 + 4*g + (j & 3);
    }
    const float* src = (p < 2) ? w1 : w2;
    float v = src[(size_t)(p & 1) * 32768 + (size_t)h * 4096 + i * 64 + o];
    g_wprep[(size_t)h * 16384 + idx] = f2bf(v);
  }
}

// ---------------- transpose 1: x [B][N][C] fp32 -> xt [B][C][N] bf16 (+inline wprep) ---
__global__ __launch_bounds__(256) void transpose_in_k(const float* __restrict__ in,
                                                      unsigned* __restrict__ out,
                                                      const float* __restrict__ w1,
                                                      const float* __restrict__ w2){
  __shared__ float tile[64][33];
  int b  = blockIdx.z;
  int c0 = blockIdx.x * 32;
  int n0 = blockIdx.y * 64;
  int t  = threadIdx.x;
  int tx = t & 31, ty = t >> 5;
  const float* src = in + ((size_t)b * NLEN + n0) * CC + c0;
  #pragma unroll
  for (int k = 0; k < 8; ++k)
    tile[ty + 8*k][tx] = src[(size_t)(ty + 8*k) * CC + tx];
  __syncthreads();
  int lt = t & 15;
  int nl = 4 * lt;
  #pragma unroll
  for (int kk = 0; kk < 2; ++kk){
    int cl = (t >> 4) + 16*kk;
    uint2 u;
    u.x = pack2t(tile[nl    ][cl], tile[nl + 1][cl]);
    u.y = pack2t(tile[nl + 2][cl], tile[nl + 3][cl]);
    *(uint2*)(out + ((size_t)(b * CC + c0 + cl) * NLEN + n0) / 2 + 2*lt) = u;
  }
  // folded weight prep: 8 designated blocks each convert one head's weights.
  if (blockIdx.x == 0 && blockIdx.z == 0 && blockIdx.y < 8)
    wprep_body(blockIdx.y, t, w1, w2);
}

// ---------------- transpose 2: yt [B][C][N] bf16 -> out [B][N][C] fp32 ----------------
__global__ __launch_bounds__(256) void transpose_out_k(const unsigned* __restrict__ in,
                                                       float* __restrict__ out){
  __shared__ float tile[64][33];
  int b  = blockIdx.z;
  int c0 = blockIdx.x * 32;
  int n0 = blockIdx.y * 64;
  int t  = threadIdx.x;
  int lt = t & 15;
  int nl = 4 * lt;
  #pragma unroll
  for (int kk = 0; kk < 2; ++kk){
    int cl = (t >> 4) + 16*kk;
    uint2 u = *(const uint2*)(in + ((size_t)(b * CC + c0 + cl) * NLEN + n0) / 2 + 2*lt);
    tile[nl    ][cl] = bflo(u.x);
    tile[nl + 1][cl] = bfhi(u.x);
    tile[nl + 2][cl] = bflo(u.y);
    tile[nl + 3][cl] = bfhi(u.y);
  }
  __syncthreads();
  int tx = t & 31, ty = t >> 5;
  float* dst = out + ((size_t)b * NLEN + n0) * CC + c0;
  #pragma unroll
  for (int k = 0; k < 8; ++k)
    dst[(size_t)(ty + 8*k) * CC + tx] = tile[ty + 8*k][tx];
}

// ================= radix-16 register FFT (N=4096, 256 threads, 3 passes) =================
// Inter-pass exchanges stored as PACKED BF16 in LDS (17.4 KB).
#define SL(e) ((e) + ((e) >> 4))
#define PERM16(p) ((((p) & 3) << 2) | ((p) >> 2))

template<int SIGN>
__device__ __forceinline__ void dft4ip(float2& v0, float2& v1, float2& v2, float2& v3){
  float2 s02 = cadd(v0, v2), d02 = csub(v0, v2);
  float2 s13 = cadd(v1, v3), d13 = csub(v1, v3);
  float2 id = make_float2(-(float)SIGN * d13.y, (float)SIGN * d13.x);
  v0 = cadd(s02, s13);
  v1 = cadd(d02, id);
  v2 = csub(s02, s13);
  v3 = csub(d02, id);
}

template<int SIGN>
__device__ __forceinline__ float2 w16c(int m){
  const float c1 = 0.9238795325112867f, s1 = 0.3826834323650898f, r = 0.7071067811865476f;
  float cs = 1.f, sn = 0.f;
  if (m == 1){ cs = c1;  sn = s1; }
  else if (m == 2){ cs = r;   sn = r; }
  else if (m == 3){ cs = s1;  sn = c1; }
  else if (m == 4){ cs = 0.f; sn = 1.f; }
  else if (m == 6){ cs = -r;  sn = r; }
  else if (m == 9){ cs = -c1; sn = -s1; }
  return make_float2(cs, (float)SIGN * sn);
}

template<int SIGN>
__device__ __forceinline__ void dft16ip(float2 v[16]){
  #pragma unroll
  for (int q0 = 0; q0 < 4; ++q0) dft4ip<SIGN>(v[q0], v[q0+4], v[q0+8], v[q0+12]);
  #pragma unroll
  for (int p0 = 0; p0 < 4; ++p0)
    #pragma unroll
    for (int q0 = 0; q0 < 4; ++q0){
      const int m = p0 * q0;
      if (m) v[q0 + 4*p0] = cmul(v[q0 + 4*p0], w16c<SIGN>(m));
    }
  #pragma unroll
  for (int p0 = 0; p0 < 4; ++p0) dft4ip<SIGN>(v[4*p0], v[4*p0+1], v[4*p0+2], v[4*p0+3]);
}

template<int SIGN>
__device__ __forceinline__ void twiddle16(float2 v[16], int jm, float invRNs){
  float ang = (float)SIGN * 6.2831853071795864769f * (float)jm * invRNs;
  float sn, cs; __sincosf(ang, &sn, &cs);
  float2 tw[16];
  tw[1] = make_float2(cs, sn);
  #pragma unroll
  for (int q = 2; q < 16; ++q) tw[q] = cmul(tw[q >> 1], tw[q - (q >> 1)]);
  #pragma unroll
  for (int q = 1; q < 16; ++q) v[q] = cmul(v[q], tw[q]);
}

// bf16-LDS exchange pass
template<int SIGN, int NS>
__device__ __forceinline__ void fft_mid_pass(unsigned* ldsb, float2 v[16], int t){
  #pragma unroll
  for (int q = 0; q < 16; ++q){
    unsigned u = ldsb[SL(t + 256*q)];
    v[q] = make_float2(bflo(u), bfhi(u));
  }
  int jm = t & (NS - 1);
  if (NS > 1) twiddle16<SIGN>(v, jm, 1.0f / (16.0f * (float)NS));
  dft16ip<SIGN>(v);
  __syncthreads();
  int base = ((t - jm) << 4) + jm;
  #pragma unroll
  for (int p = 0; p < 16; ++p){
    float2 w = v[PERM16(p)];
    ldsb[SL(base + p*NS)] = pack2t(w.x, w.y);
  }
  __syncthreads();
}

#define ORTHO_S 0.011048543456039806f   // 1/sqrt(8192)

// ---------------- forward rfft-8192: xt bf16 row -> tile-blocked spec bins ----------------
__global__ __launch_bounds__(256) void fft_fwd_k(const unsigned* __restrict__ xt,
                                                 unsigned* __restrict__ spec){
  __shared__ unsigned ldsb[4352];
  int t = threadIdx.x;
  size_t row = blockIdx.x;
  const unsigned* src = xt + row * (NLEN/2);
  float2 v[16];
  #pragma unroll
  for (int q = 0; q < 16; ++q){
    unsigned u = src[t + 256*q];
    v[q] = make_float2(bflo(u), bfhi(u));
  }
  dft16ip<-1>(v);
  #pragma unroll
  for (int p = 0; p < 16; ++p){
    float2 w = v[PERM16(p)];
    ldsb[SL(16*t + p)] = pack2t(w.x, w.y);
  }
  __syncthreads();
  fft_mid_pass<-1, 16 >(ldsb, v, t);
  fft_mid_pass<-1, 256>(ldsb, v, t);
  unsigned* dst = spec + (row >> 6) * (size_t)BHSZ + (row & 63) * 64;
  float snb, csb;
  __sincosf(-6.2831853071795864769f * (float)t / (float)NLEN, &snb, &csb);
  #pragma unroll
  for (int q = 0; q < 8; ++q){
    int k = t + 256*q;
    unsigned uk = ldsb[SL(k)];
    unsigned uc = ldsb[SL((MH - k) & (MH - 1))];
    float2 zk = make_float2(bflo(uk), bfhi(uk));
    float2 zc = make_float2(bflo(uc), bfhi(uc));
    float ex = 0.5f*(zk.x + zc.x);
    float ey = 0.5f*(zk.y - zc.y);
    float ox =  0.5f*(zk.y + zc.y);
    float oy = -0.5f*(zk.x - zc.x);
    float cs = fmaf(csb, C32C[q],  snb*C32S[q]);
    float sn = fmaf(snb, C32C[q], -csb*C32S[q]);
    float P = cs*ox - sn*oy;
    float Q = cs*oy + sn*ox;
    dst[KADDR(k)]      = pack2t(ORTHO_S*(ex + P), ORTHO_S*(ey + Q));
    dst[KADDR(MH - k)] = pack2t(ORTHO_S*(ex - P), ORTHO_S*(Q - ey));
  }
  if (t == 0){
    unsigned um = ldsb[SL(2048)];
    dst[KADDR(2048)] = pack2t(ORTHO_S*bflo(um), -ORTHO_S*bfhi(um));
  }
}

// ---------------- inverse rfft-8192: tile-blocked spec bins -> yt bf16 row ----------------
__global__ __launch_bounds__(256) void fft_inv_k(const unsigned* __restrict__ spec,
                                                 unsigned* __restrict__ yt){
  __shared__ unsigned ldsb[4352];
  int t = threadIdx.x;
  size_t row = blockIdx.x;
  const unsigned* src = spec + (row >> 6) * (size_t)BHSZ + (row & 63) * 64;
  float snb, csb;
  __sincosf(6.2831853071795864769f * (float)t / (float)NLEN, &snb, &csb);
  snb *= ORTHO_S; csb *= ORTHO_S;                         // fold ortho scale
  #pragma unroll
  for (int q = 0; q < 8; ++q){
    int k = t + 256*q;
    unsigned uk = src[KADDR(k)];
    unsigned uc = src[KADDR(MH - k)];
    float2 xk = make_float2(bflo(uk), bfhi(uk));
    float2 xc = make_float2(bflo(uc), bfhi(uc));
    if (k == 0){ xk.y = 0.0f; xc.y = 0.0f; }
    float ex = ORTHO_S*(xk.x + xc.x);
    float ey = ORTHO_S*(xk.y - xc.y);
    float dx = xk.x - xc.x;
    float dy = xk.y + xc.y;
    float cs = fmaf(csb, C32C[q], -snb*C32S[q]);          // ORTHO_S * rot
    float sn = fmaf(snb, C32C[q],  csb*C32S[q]);
    float ox = cs*dx - sn*dy;
    float oy = cs*dy + sn*dx;
    ldsb[SL(k)] = pack2t(ex - oy, ey + ox);               // ORTHO_S * Z[k]
    if (k > 0)
      ldsb[SL(MH - k)] = pack2t(ex + oy, ox - ey);        // ORTHO_S * Z[4096-k]
  }
  if (t == 0){                               // self-dual m=2048
    unsigned um = src[KADDR(2048)];
    ldsb[SL(2048)] = pack2t(2.0f*ORTHO_S*bflo(um), -2.0f*ORTHO_S*bfhi(um));
  }
  __syncthreads();
  float2 v[16];
  fft_mid_pass<1, 1  >(ldsb, v, t);
  fft_mid_pass<1, 16 >(ldsb, v, t);
  fft_mid_pass<1, 256>(ldsb, v, t);
  uint4* d4 = (uint4*)(yt + row * (NLEN/2) + 16*t);
  #pragma unroll
  for (int g = 0; g < 4; ++g){
    uint4 stv;
    stv.x = ldsb[SL(16*t + 4*g    )];
    stv.y = ldsb[SL(16*t + 4*g + 1)];
    stv.z = ldsb[SL(16*t + 4*g + 2)];
    stv.w = ldsb[SL(16*t + 4*g + 3)];
    d4[g] = stv;
  }
}

// ---------------- middle: 1024-thread / 4-parallel-tile MFMA MLP ----------------
// Four wave-groups (4 waves each) own one tile apiece; ONE shared W stage + barrier.
#define WP 72
#define WPLANE 4608          // 64*72 shorts per plane
__global__ __launch_bounds__(1024) void afno_mid_mfma_k(const unsigned* __restrict__ spec_in,
                                                        unsigned* __restrict__ spec_out,
                                                        const float* __restrict__ b1,
                                                        const float* __restrict__ b2){
  __shared__ unsigned short Wl[4 * WPLANE];              // 36,864 B (shared by all 4 tiles)
  const int t = threadIdx.x;
  const int bx = blockIdx.x, h = blockIdx.y, b = blockIdx.z;
  const size_t bhbase = (size_t)(b * HH + h) * BHSZ;
  const int l = t & 63, wv = t >> 6;                     // wv in 0..15
  const int wg = wv >> 2, wv4 = wv & 3;                  // tile-group (0..3), wave-in-group
  const int lf = l & 15, lg = l >> 4;
  const int wf0 = wv4 * 16;
  const int tile = bx * 4 + wg;                          // 0..67 (65..67 = phantom)
  const int tload = (tile <= 64) ? tile : 64;

  // ---- issue X fragment loads FIRST from the contiguous tile ----
  const unsigned* xblk = spec_in + bhbase + (size_t)tload * 4096;
  unsigned bins[16];
  #pragma unroll
  for (int ks = 0; ks < 2; ++ks){
    int i0 = (ks*4 + lg) * 8;
    #pragma unroll
    for (int j = 0; j < 8; ++j)
      bins[ks*8 + j] = xblk[(i0 + j)*64 + wf0 + lf];
  }

  // ---- stage W once into padded LDS (2048 16B chunks over 1024 threads) ----
  {
    const uint4* gw = (const uint4*)(g_wprep + (size_t)h * 16384);
    #pragma unroll
    for (int u = 0; u < 2; ++u){
      int c = t + 1024*u;                  // (p, o, blk)
      int p = c >> 9, o = (c >> 3) & 63, blk = c & 7;
      *(uint4*)(Wl + p*WPLANE + o*WP + blk*8) = gw[c];
    }
  }
  // ---- hoist biases ----
  float4 br1[4], bi1[4];
  #pragma unroll
  for (int mt = 0; mt < 4; ++mt){
    br1[mt] = *(const float4*)(b1 +       (size_t)h*64 + mt*16 + lg*4);
    bi1[mt] = *(const float4*)(b1 + 512 + (size_t)h*64 + mt*16 + lg*4);
  }
  float b2r[4], b2i[4];
  #pragma unroll
  for (int nt = 0; nt < 4; ++nt){
    b2r[nt] = b2[(size_t)h*64 + nt*16 + lf];
    b2i[nt] = b2[512 + (size_t)h*64 + nt*16 + lf];
  }
  __syncthreads();

  const unsigned short* W1R = Wl;
  const unsigned short* W1I = Wl + WPLANE;
  const unsigned short* W2R = Wl + 2*WPLANE;
  const unsigned short* W2I = Wl + 3*WPLANE;
  const f32x4 zz = {0.f, 0.f, 0.f, 0.f};

  f32x4 a1R[4], a1I[4];
  #pragma unroll
  for (int mt = 0; mt < 4; ++mt){ a1R[mt] = zz; a1I[mt] = zz; }

  // -------- stage 1: O1^T = W1^T X^T --------
  #pragma unroll
  for (int ks = 0; ks < 2; ++ks){
    u32x4 pr, pi;
    pr.x = __builtin_amdgcn_perm(bins[ks*8+1], bins[ks*8+0], 0x05040100u);
    pr.y = __builtin_amdgcn_perm(bins[ks*8+3], bins[ks*8+2], 0x05040100u);
    pr.z = __builtin_amdgcn_perm(bins[ks*8+5], bins[ks*8+4], 0x05040100u);
    pr.w = __builtin_amdgcn_perm(bins[ks*8+7], bins[ks*8+6], 0x05040100u);
    pi.x = __builtin_amdgcn_perm(bins[ks*8+1], bins[ks*8+0], 0x07060302u);
    pi.y = __builtin_amdgcn_perm(bins[ks*8+3], bins[ks*8+2], 0x07060302u);
    pi.z = __builtin_amdgcn_perm(bins[ks*8+5], bins[ks*8+4], 0x07060302u);
    pi.w = __builtin_amdgcn_perm(bins[ks*8+7], bins[ks*8+6], 0x07060302u);
    bf16x8 bxr = __builtin_bit_cast(bf16x8, pr);
    bf16x8 bxi = __builtin_bit_cast(bf16x8, pi);
    int b0 = ks*4 + lg;
    #pragma unroll
    for (int mt = 0; mt < 4; ++mt){
      int o = mt*16 + lf;
      int swo = (o ^ (o >> 3)) & 7;
      int off = o*WP + ((b0 ^ swo) << 3);
      bf16x8 awr  = *(const bf16x8*)(W1R + off);
      bf16x8 awi  = *(const bf16x8*)(W1I + off);
      bf16x8 awin = awi ^ (short)0x8000;
      a1R[mt] = MFMA(awr,  bxr, a1R[mt]);
      a1R[mt] = MFMA(awin, bxi, a1R[mt]);
      a1I[mt] = MFMA(awi,  bxr, a1I[mt]);
      a1I[mt] = MFMA(awr,  bxi, a1I[mt]);
    }
  }

  // -------- stage-1 epilogue: bias + GELU -> stage-2 A-fragments --------
  bf16x8 aFr[2], aFi[2], aFin[2];
  #pragma unroll
  for (int ks = 0; ks < 2; ++ks){
    const int m0 = 2*ks, m1 = 2*ks + 1;
    u32x4 wr4, wi4;
    wr4.x = pack2t(gelu_fast(a1R[m0][0] + br1[m0].x), gelu_fast(a1R[m0][1] + br1[m0].y));
    wr4.y = pack2t(gelu_fast(a1R[m0][2] + br1[m0].z), gelu_fast(a1R[m0][3] + br1[m0].w));
    wr4.z = pack2t(gelu_fast(a1R[m1][0] + br1[m1].x), gelu_fast(a1R[m1][1] + br1[m1].y));
    wr4.w = pack2t(gelu_fast(a1R[m1][2] + br1[m1].z), gelu_fast(a1R[m1][3] + br1[m1].w));
    wi4.x = pack2t(gelu_fast(a1I[m0][0] + bi1[m0].x), gelu_fast(a1I[m0][1] + bi1[m0].y));
    wi4.y = pack2t(gelu_fast(a1I[m0][2] + bi1[m0].z), gelu_fast(a1I[m0][3] + bi1[m0].w));
    wi4.z = pack2t(gelu_fast(a1I[m1][0] + bi1[m1].x), gelu_fast(a1I[m1][1] + bi1[m1].y));
    wi4.w = pack2t(gelu_fast(a1I[m1][2] + bi1[m1].z), gelu_fast(a1I[m1][3] + bi1[m1].w));
    aFr[ks]  = __builtin_bit_cast(bf16x8, wr4);
    aFi[ks]  = __builtin_bit_cast(bf16x8, wi4);
    aFin[ks] = aFi[ks] ^ (short)0x8000;
  }

  // -------- stage 2: O2 = O1 W2 --------
  f32x4 a2R[4], a2I[4];
  #pragma unroll
  for (int nt = 0; nt < 4; ++nt){ a2R[nt] = zz; a2I[nt] = zz; }
  #pragma unroll
  for (int ks = 0; ks < 2; ++ks){
    int b0 = ks*4 + lg;
    #pragma unroll
    for (int nt = 0; nt < 4; ++nt){
      int o2 = nt*16 + lf;
      int swo = (o2 ^ (o2 >> 3)) & 7;
      int off = o2*WP + ((b0 ^ swo) << 3);
      bf16x8 bwr = *(const bf16x8*)(W2R + off);
      bf16x8 bwi = *(const bf16x8*)(W2I + off);
      a2R[nt] = MFMA(aFr[ks],  bwr, a2R[nt]);
      a2R[nt] = MFMA(aFin[ks], bwi, a2R[nt]);
      a2I[nt] = MFMA(aFi[ks],  bwr, a2I[nt]);
      a2I[nt] = MFMA(aFr[ks],  bwi, a2I[nt]);
    }
  }

  // -------- stage-2 epilogue: bias + contiguous 16B tile stores (guarded) --------
  if (tile <= 64){
    unsigned* oblk = spec_out + bhbase + (size_t)tile * 4096;
    int fl0 = wf0 + lg*4;
    #pragma unroll
    for (int nt = 0; nt < 4; ++nt){
      int o2 = nt*16 + lf;
      uint4 st;
      st.x = pack2t(a2R[nt][0] + b2r[nt], a2I[nt][0] + b2i[nt]);
      st.y = pack2t(a2R[nt][1] + b2r[nt], a2I[nt][1] + b2i[nt]);
      st.z = pack2t(a2R[nt][2] + b2r[nt], a2I[nt][2] + b2i[nt]);
      st.w = pack2t(a2R[nt][3] + b2r[nt], a2I[nt][3] + b2i[nt]);
      *(uint4*)(oblk + o2*64 + fl0) = st;
    }
  }
}

// ---------------- launch ----------------
extern "C" void kernel_launch(void* const* d_in, const int* in_sizes, int n_in,
                              void* d_out, int out_size, void* d_ws, size_t ws_size,
                              hipStream_t stream) {
  const float* x  = (const float*)d_in[0];
  const float* w1 = (const float*)d_in[1];
  const float* b1 = (const float*)d_in[2];
  const float* w2 = (const float*)d_in[3];
  const float* b2 = (const float*)d_in[4];
  float* out = (float*)d_out;

  unsigned char* base = (unsigned char*)d_ws;
  if (ws_size < 2 * REGION_BYTES){
    void* p = nullptr;
    hipGetSymbolAddress(&p, HIP_SYMBOL(g_scratch));
    base = (unsigned char*)p;
  }
  unsigned* specA = (unsigned*)base;                 // region A: spectrum1, later yt
  unsigned char* regB = base + REGION_BYTES;         // region B: xt, later spectrum2
  unsigned* xt    = (unsigned*)regB;
  unsigned* specB = (unsigned*)regB;
  unsigned* ytp   = (unsigned*)base;

  // 1) transpose x -> xt (wprep folded into 8 designated blocks)
  transpose_in_k<<<dim3(CC/32, NLEN/64, BB), 256, 0, stream>>>(x, xt, w1, w2);
  // 2) forward rfft -> tile-blocked spectrum (bf16 LDS exchanges)
  fft_fwd_k<<<NSEQ, 256, 0, stream>>>(xt, specA);
  // 3) complex MLP (1024 threads, 4 parallel tiles/block, shared W stage)
  afno_mid_mfma_k<<<dim3(17, HH, BB), 1024, 0, stream>>>(specA, specB, b1, b2);
  // 4) inverse rfft (bf16 LDS exchanges, folded ortho scale)
  fft_inv_k<<<NSEQ, 256, 0, stream>>>(specB, ytp);
  // 5) transpose yt -> out
  transpose_out_k<<<dim3(CC/32, NLEN/64, BB), 256, 0, stream>>>(ytp, out);
}

// Round 25
// 175.114 us; speedup vs baseline: 1.0657x; 1.0657x over previous
//
#include <hip/hip_runtime.h>
#include <math.h>

// ---------------- problem constants ----------------
#define BB    8
#define NLEN  8192          // sequence length (FFT size)
#define CC    512           // channels
#define HH    8             // heads
#define DH    64            // head dim
#define MH    4096          // NLEN/2 (complex FFT size)
#define FREQ  4097          // rfft bins
#define FP    4160          // region-sizing row equivalent (65 tiles * 64)
#define NSEQ  (BB*CC)       // 4096 rows
#define BHSZ  (65*4096)     // uints per (b,h) group: 65 f-tiles x [i=64][f=64]

// spectrum layout: [b][h][ftile][i][f] bf16-pair bins
#define KADDR(k) ((((k) >> 6) << 12) + ((k) & 63))

// scratch: two regions of NSEQ*FP uint
#define REGION_BYTES ((size_t)NSEQ * FP * 4ull)

static __device__ __align__(256) unsigned char g_scratch[2ull * (size_t)NSEQ * FP * 4ull];
// prepped weights: [h][plane(0=w1r,1=w1i,2=w2r,3=w2i)][o][swizzled k-slot] bf16
__device__ unsigned short g_wprep[8 * 4 * 64 * 64];

typedef __attribute__((ext_vector_type(8))) short bf16x8;
typedef __attribute__((ext_vector_type(4))) float f32x4;
typedef __attribute__((ext_vector_type(4))) unsigned u32x4;

__device__ __forceinline__ f32x4 MFMA(bf16x8 a, bf16x8 b, f32x4 c){
  return __builtin_amdgcn_mfma_f32_16x16x32_bf16(a, b, c, 0, 0, 0);
}

__device__ __forceinline__ unsigned short f2bf(float f){   // rne (wprep only)
  unsigned u = __float_as_uint(f);
  return (unsigned short)((u + 0x7fffu + ((u >> 16) & 1u)) >> 16);
}
// truncating bf16 pack: ONE v_perm (takes high halves of a,b)
__device__ __forceinline__ unsigned pack2t(float a, float b){
  return __builtin_amdgcn_perm(__float_as_uint(b), __float_as_uint(a), 0x07060302u);
}
__device__ __forceinline__ float bflo(unsigned u){ return __uint_as_float(u << 16); }
__device__ __forceinline__ float bfhi(unsigned u){ return __uint_as_float(u & 0xffff0000u); }

// cos/sin(2*pi*q/32) for q=0..15
__device__ const float C32C[16] = {
  1.f, 0.98078528f, 0.92387953f, 0.83146961f, 0.70710678f, 0.55557023f,
  0.38268343f, 0.19509032f, 0.f, -0.19509032f, -0.38268343f, -0.55557023f,
  -0.70710678f, -0.83146961f, -0.92387953f, -0.98078528f};
__device__ const float C32S[16] = {
  0.f, 0.19509032f, 0.38268343f, 0.55557023f, 0.70710678f, 0.83146961f,
  0.92387953f, 0.98078528f, 1.f, 0.98078528f, 0.92387953f, 0.83146961f,
  0.70710678f, 0.55557023f, 0.38268343f, 0.19509032f};

// cheap GELU: v * sigmoid(1.702 v)
__device__ __forceinline__ float gelu_fast(float v){
  float e = __builtin_amdgcn_exp2f(-2.4554572f * v);     // exp(-1.702 v)
  return v * __builtin_amdgcn_rcpf(1.0f + e);
}

// ---------------- complex helpers ----------------
__device__ __forceinline__ float2 cadd(float2 a, float2 b){ return make_float2(a.x+b.x, a.y+b.y); }
__device__ __forceinline__ float2 csub(float2 a, float2 b){ return make_float2(a.x-b.x, a.y-b.y); }
__device__ __forceinline__ float2 cmul(float2 a, float2 b){
  return make_float2(fmaf(a.x, b.x, -(a.y*b.y)), fmaf(a.x, b.y, a.y*b.x));
}

// ---------------- weight prep body (called from 8 transpose blocks) ----------------
__device__ __forceinline__ void wprep_body(int h, int t,
                                           const float* __restrict__ w1,
                                           const float* __restrict__ w2){
  #pragma unroll 4
  for (int u = 0; u < 64; ++u){
    int idx = t + 256*u;
    int p = idx >> 12;
    int o = (idx >> 6) & 63;
    int jj = idx & 63;
    int swo = (o ^ (o >> 3)) & 7;
    int s = (((jj >> 3) ^ swo) << 3) | (jj & 7);
    int i;
    if (p < 2){
      i = s;
    } else {
      int ks = s >> 5, g = (s >> 3) & 3, j = s & 7;
      i = (2*ks + (j >> 2))*16 + 4*g + (j & 3);
    }
    const float* src = (p < 2) ? w1 : w2;
    float v = src[(size_t)(p & 1) * 32768 + (size_t)h * 4096 + i * 64 + o];
    g_wprep[(size_t)h * 16384 + idx] = f2bf(v);
  }
}

// ---------------- transpose 1: x [B][N][C] fp32 -> xt [B][C][N] bf16 (+inline wprep) ---
__global__ __launch_bounds__(256) void transpose_in_k(const float* __restrict__ in,
                                                      unsigned* __restrict__ out,
                                                      const float* __restrict__ w1,
                                                      const float* __restrict__ w2){
  __shared__ float tile[64][33];
  int b  = blockIdx.z;
  int c0 = blockIdx.x * 32;
  int n0 = blockIdx.y * 64;
  int t  = threadIdx.x;
  int tx = t & 31, ty = t >> 5;
  const float* src = in + ((size_t)b * NLEN + n0) * CC + c0;
  #pragma unroll
  for (int k = 0; k < 8; ++k)
    tile[ty + 8*k][tx] = src[(size_t)(ty + 8*k) * CC + tx];
  __syncthreads();
  int lt = t & 15;
  int nl = 4 * lt;
  #pragma unroll
  for (int kk = 0; kk < 2; ++kk){
    int cl = (t >> 4) + 16*kk;
    uint2 u;
    u.x = pack2t(tile[nl    ][cl], tile[nl + 1][cl]);
    u.y = pack2t(tile[nl + 2][cl], tile[nl + 3][cl]);
    *(uint2*)(out + ((size_t)(b * CC + c0 + cl) * NLEN + n0) / 2 + 2*lt) = u;
  }
  // folded weight prep: 8 designated blocks each convert one head's weights.
  if (blockIdx.x == 0 && blockIdx.z == 0 && blockIdx.y < 8)
    wprep_body(blockIdx.y, t, w1, w2);
}

// ---------------- transpose 2: yt [B][C][N] bf16 -> out [B][N][C] fp32 ----------------
__global__ __launch_bounds__(256) void transpose_out_k(const unsigned* __restrict__ in,
                                                       float* __restrict__ out){
  __shared__ float tile[64][33];
  int b  = blockIdx.z;
  int c0 = blockIdx.x * 32;
  int n0 = blockIdx.y * 64;
  int t  = threadIdx.x;
  int lt = t & 15;
  int nl = 4 * lt;
  #pragma unroll
  for (int kk = 0; kk < 2; ++kk){
    int cl = (t >> 4) + 16*kk;
    uint2 u = *(const uint2*)(in + ((size_t)(b * CC + c0 + cl) * NLEN + n0) / 2 + 2*lt);
    tile[nl    ][cl] = bflo(u.x);
    tile[nl + 1][cl] = bfhi(u.x);
    tile[nl + 2][cl] = bflo(u.y);
    tile[nl + 3][cl] = bfhi(u.y);
  }
  __syncthreads();
  int tx = t & 31, ty = t >> 5;
  float* dst = out + ((size_t)b * NLEN + n0) * CC + c0;
  #pragma unroll
  for (int k = 0; k < 8; ++k)
    dst[(size_t)(ty + 8*k) * CC + tx] = tile[ty + 8*k][tx];
}

// ================= radix-16 register FFT (N=4096, 256 threads, 3 passes) =================
// Inter-pass exchanges stored as PACKED BF16 in LDS (17.4 KB).
#define SL(e) ((e) + ((e) >> 4))
#define PERM16(p) ((((p) & 3) << 2) | ((p) >> 2))

template<int SIGN>
__device__ __forceinline__ void dft4ip(float2& v0, float2& v1, float2& v2, float2& v3){
  float2 s02 = cadd(v0, v2), d02 = csub(v0, v2);
  float2 s13 = cadd(v1, v3), d13 = csub(v1, v3);
  float2 id = make_float2(-(float)SIGN * d13.y, (float)SIGN * d13.x);
  v0 = cadd(s02, s13);
  v1 = cadd(d02, id);
  v2 = csub(s02, s13);
  v3 = csub(d02, id);
}

template<int SIGN>
__device__ __forceinline__ float2 w16c(int m){
  const float c1 = 0.9238795325112867f, s1 = 0.3826834323650898f, r = 0.7071067811865476f;
  float cs = 1.f, sn = 0.f;
  if (m == 1){ cs = c1;  sn = s1; }
  else if (m == 2){ cs = r;   sn = r; }
  else if (m == 3){ cs = s1;  sn = c1; }
  else if (m == 4){ cs = 0.f; sn = 1.f; }
  else if (m == 6){ cs = -r;  sn = r; }
  else if (m == 9){ cs = -c1; sn = -s1; }
  return make_float2(cs, (float)SIGN * sn);
}

template<int SIGN>
__device__ __forceinline__ void dft16ip(float2 v[16]){
  #pragma unroll
  for (int q0 = 0; q0 < 4; ++q0) dft4ip<SIGN>(v[q0], v[q0+4], v[q0+8], v[q0+12]);
  #pragma unroll
  for (int p0 = 0; p0 < 4; ++p0)
    #pragma unroll
    for (int q0 = 0; q0 < 4; ++q0){
      const int m = p0 * q0;
      if (m) v[q0 + 4*p0] = cmul(v[q0 + 4*p0], w16c<SIGN>(m));
    }
  #pragma unroll
  for (int p0 = 0; p0 < 4; ++p0) dft4ip<SIGN>(v[4*p0], v[4*p0+1], v[4*p0+2], v[4*p0+3]);
}

template<int SIGN>
__device__ __forceinline__ void twiddle16(float2 v[16], int jm, float invRNs){
  float ang = (float)SIGN * 6.2831853071795864769f * (float)jm * invRNs;
  float sn, cs; __sincosf(ang, &sn, &cs);
  float2 tw[16];
  tw[1] = make_float2(cs, sn);
  #pragma unroll
  for (int q = 2; q < 16; ++q) tw[q] = cmul(tw[q >> 1], tw[q - (q >> 1)]);
  #pragma unroll
  for (int q = 1; q < 16; ++q) v[q] = cmul(v[q], tw[q]);
}

// bf16-LDS exchange pass
template<int SIGN, int NS>
__device__ __forceinline__ void fft_mid_pass(unsigned* ldsb, float2 v[16], int t){
  #pragma unroll
  for (int q = 0; q < 16; ++q){
    unsigned u = ldsb[SL(t + 256*q)];
    v[q] = make_float2(bflo(u), bfhi(u));
  }
  int jm = t & (NS - 1);
  if (NS > 1) twiddle16<SIGN>(v, jm, 1.0f / (16.0f * (float)NS));
  dft16ip<SIGN>(v);
  __syncthreads();
  int base = ((t - jm) << 4) + jm;
  #pragma unroll
  for (int p = 0; p < 16; ++p){
    float2 w = v[PERM16(p)];
    ldsb[SL(base + p*NS)] = pack2t(w.x, w.y);
  }
  __syncthreads();
}

#define ORTHO_S 0.011048543456039806f   // 1/sqrt(8192)

// ---------------- forward rfft-8192: xt bf16 row -> tile-blocked spec bins ----------------
__global__ __launch_bounds__(256) void fft_fwd_k(const unsigned* __restrict__ xt,
                                                 unsigned* __restrict__ spec){
  __shared__ unsigned ldsb[4352];
  int t = threadIdx.x;
  size_t row = blockIdx.x;
  const unsigned* src = xt + row * (NLEN/2);
  float2 v[16];
  #pragma unroll
  for (int q = 0; q < 16; ++q){
    unsigned u = src[t + 256*q];
    v[q] = make_float2(bflo(u), bfhi(u));
  }
  dft16ip<-1>(v);
  #pragma unroll
  for (int p = 0; p < 16; ++p){
    float2 w = v[PERM16(p)];
    ldsb[SL(16*t + p)] = pack2t(w.x, w.y);
  }
  __syncthreads();
  fft_mid_pass<-1, 16 >(ldsb, v, t);
  fft_mid_pass<-1, 256>(ldsb, v, t);
  unsigned* dst = spec + (row >> 6) * (size_t)BHSZ + (row & 63) * 64;
  float snb, csb;
  __sincosf(-6.2831853071795864769f * (float)t / (float)NLEN, &snb, &csb);
  #pragma unroll
  for (int q = 0; q < 8; ++q){
    int k = t + 256*q;
    unsigned uk = ldsb[SL(k)];
    unsigned uc = ldsb[SL((MH - k) & (MH - 1))];
    float2 zk = make_float2(bflo(uk), bfhi(uk));
    float2 zc = make_float2(bflo(uc), bfhi(uc));
    float ex = 0.5f*(zk.x + zc.x);
    float ey = 0.5f*(zk.y - zc.y);
    float ox =  0.5f*(zk.y + zc.y);
    float oy = -0.5f*(zk.x - zc.x);
    float cs = fmaf(csb, C32C[q],  snb*C32S[q]);
    float sn = fmaf(snb, C32C[q], -csb*C32S[q]);
    float P = cs*ox - sn*oy;
    float Q = cs*oy + sn*ox;
    dst[KADDR(k)]      = pack2t(ORTHO_S*(ex + P), ORTHO_S*(ey + Q));
    dst[KADDR(MH - k)] = pack2t(ORTHO_S*(ex - P), ORTHO_S*(Q - ey));
  }
  if (t == 0){
    unsigned um = ldsb[SL(2048)];
    dst[KADDR(2048)] = pack2t(ORTHO_S*bflo(um), -ORTHO_S*bfhi(um));
  }
}

// ---------------- inverse rfft-8192: tile-blocked spec bins -> yt bf16 row ----------------
__global__ __launch_bounds__(256) void fft_inv_k(const unsigned* __restrict__ spec,
                                                 unsigned* __restrict__ yt){
  __shared__ unsigned ldsb[4352];
  int t = threadIdx.x;
  size_t row = blockIdx.x;
  const unsigned* src = spec + (row >> 6) * (size_t)BHSZ + (row & 63) * 64;
  float snb, csb;
  __sincosf(6.2831853071795864769f * (float)t / (float)NLEN, &snb, &csb);
  snb *= ORTHO_S; csb *= ORTHO_S;                         // fold ortho scale
  #pragma unroll
  for (int q = 0; q < 8; ++q){
    int k = t + 256*q;
    unsigned uk = src[KADDR(k)];
    unsigned uc = src[KADDR(MH - k)];
    float2 xk = make_float2(bflo(uk), bfhi(uk));
    float2 xc = make_float2(bflo(uc), bfhi(uc));
    if (k == 0){ xk.y = 0.0f; xc.y = 0.0f; }
    float ex = ORTHO_S*(xk.x + xc.x);
    float ey = ORTHO_S*(xk.y - xc.y);
    float dx = xk.x - xc.x;
    float dy = xk.y + xc.y;
    float cs = fmaf(csb, C32C[q], -snb*C32S[q]);          // ORTHO_S * rot
    float sn = fmaf(snb, C32C[q],  csb*C32S[q]);
    float ox = cs*dx - sn*dy;
    float oy = cs*dy + sn*dx;
    ldsb[SL(k)] = pack2t(ex - oy, ey + ox);               // ORTHO_S * Z[k]
    if (k > 0)
      ldsb[SL(MH - k)] = pack2t(ex + oy, ox - ey);        // ORTHO_S * Z[4096-k]
  }
  if (t == 0){                               // self-dual m=2048
    unsigned um = src[KADDR(2048)];
    ldsb[SL(2048)] = pack2t(2.0f*ORTHO_S*bflo(um), -2.0f*ORTHO_S*bfhi(um));
  }
  __syncthreads();
  float2 v[16];
  fft_mid_pass<1, 1  >(ldsb, v, t);
  fft_mid_pass<1, 16 >(ldsb, v, t);
  fft_mid_pass<1, 256>(ldsb, v, t);
  uint4* d4 = (uint4*)(yt + row * (NLEN/2) + 16*t);
  #pragma unroll
  for (int g = 0; g < 4; ++g){
    uint4 stv;
    stv.x = ldsb[SL(16*t + 4*g    )];
    stv.y = ldsb[SL(16*t + 4*g + 1)];
    stv.z = ldsb[SL(16*t + 4*g + 2)];
    stv.w = ldsb[SL(16*t + 4*g + 3)];
    d4[g] = stv;
  }
}

// ---------------- middle: 512-thread / 2-parallel-tile MFMA MLP ----------------
#define WP 72
#define WPLANE 4608          // 64*72 shorts per plane
__global__ __launch_bounds__(512) void afno_mid_mfma_k(const unsigned* __restrict__ spec_in,
                                                       unsigned* __restrict__ spec_out,
                                                       const float* __restrict__ b1,
                                                       const float* __restrict__ b2){
  __shared__ unsigned short Wl[4 * WPLANE];              // 36,864 B (shared by both tiles)
  const int t = threadIdx.x;
  const int bx = blockIdx.x, h = blockIdx.y, b = blockIdx.z;
  const size_t bhbase = (size_t)(b * HH + h) * BHSZ;
  const int l = t & 63, wv = t >> 6;                     // wv in 0..7
  const int wg = wv >> 2, wv4 = wv & 3;                  // tile-group, wave-in-group
  const int lf = l & 15, lg = l >> 4;
  const int wf0 = wv4 * 16;
  const int tile = bx * 2 + wg;                          // 0..65 (65 = phantom)
  const int tload = (tile <= 64) ? tile : 64;

  // ---- issue X fragment loads FIRST from the contiguous tile ----
  const unsigned* xblk = spec_in + bhbase + (size_t)tload * 4096;
  unsigned bins[16];
  #pragma unroll
  for (int ks = 0; ks < 2; ++ks){
    int i0 = (ks*4 + lg) * 8;
    #pragma unroll
    for (int j = 0; j < 8; ++j)
      bins[ks*8 + j] = xblk[(i0 + j)*64 + wf0 + lf];
  }

  // ---- stage W once into padded LDS (2048 16B chunks over 512 threads) ----
  {
    const uint4* gw = (const uint4*)(g_wprep + (size_t)h * 16384);
    #pragma unroll
    for (int u = 0; u < 4; ++u){
      int c = t + 512*u;                   // (p, o, blk)
      int p = c >> 9, o = (c >> 3) & 63, blk = c & 7;
      *(uint4*)(Wl + p*WPLANE + o*WP + blk*8) = gw[c];
    }
  }
  // ---- hoist biases ----
  float4 br1[4], bi1[4];
  #pragma unroll
  for (int mt = 0; mt < 4; ++mt){
    br1[mt] = *(const float4*)(b1 +       (size_t)h*64 + mt*16 + lg*4);
    bi1[mt] = *(const float4*)(b1 + 512 + (size_t)h*64 + mt*16 + lg*4);
  }
  float b2r[4], b2i[4];
  #pragma unroll
  for (int nt = 0; nt < 4; ++nt){
    b2r[nt] = b2[(size_t)h*64 + nt*16 + lf];
    b2i[nt] = b2[512 + (size_t)h*64 + nt*16 + lf];
  }
  __syncthreads();

  const unsigned short* W1R = Wl;
  const unsigned short* W1I = Wl + WPLANE;
  const unsigned short* W2R = Wl + 2*WPLANE;
  const unsigned short* W2I = Wl + 3*WPLANE;
  const f32x4 zz = {0.f, 0.f, 0.f, 0.f};

  f32x4 a1R[4], a1I[4];
  #pragma unroll
  for (int mt = 0; mt < 4; ++mt){ a1R[mt] = zz; a1I[mt] = zz; }

  // -------- stage 1: O1^T = W1^T X^T --------
  #pragma unroll
  for (int ks = 0; ks < 2; ++ks){
    u32x4 pr, pi;
    pr.x = __builtin_amdgcn_perm(bins[ks*8+1], bins[ks*8+0], 0x05040100u);
    pr.y = __builtin_amdgcn_perm(bins[ks*8+3], bins[ks*8+2], 0x05040100u);
    pr.z = __builtin_amdgcn_perm(bins[ks*8+5], bins[ks*8+4], 0x05040100u);
    pr.w = __builtin_amdgcn_perm(bins[ks*8+7], bins[ks*8+6], 0x05040100u);
    pi.x = __builtin_amdgcn_perm(bins[ks*8+1], bins[ks*8+0], 0x07060302u);
    pi.y = __builtin_amdgcn_perm(bins[ks*8+3], bins[ks*8+2], 0x07060302u);
    pi.z = __builtin_amdgcn_perm(bins[ks*8+5], bins[ks*8+4], 0x07060302u);
    pi.w = __builtin_amdgcn_perm(bins[ks*8+7], bins[ks*8+6], 0x07060302u);
    bf16x8 bxr = __builtin_bit_cast(bf16x8, pr);
    bf16x8 bxi = __builtin_bit_cast(bf16x8, pi);
    int b0 = ks*4 + lg;
    #pragma unroll
    for (int mt = 0; mt < 4; ++mt){
      int o = mt*16 + lf;
      int swo = (o ^ (o >> 3)) & 7;
      int off = o*WP + ((b0 ^ swo) << 3);
      bf16x8 awr  = *(const bf16x8*)(W1R + off);
      bf16x8 awi  = *(const bf16x8*)(W1I + off);
      bf16x8 awin = awi ^ (short)0x8000;
      a1R[mt] = MFMA(awr,  bxr, a1R[mt]);
      a1R[mt] = MFMA(awin, bxi, a1R[mt]);
      a1I[mt] = MFMA(awi,  bxr, a1I[mt]);
      a1I[mt] = MFMA(awr,  bxi, a1I[mt]);
    }
  }

  // -------- stage-1 epilogue: bias + GELU -> stage-2 A-fragments --------
  bf16x8 aFr[2], aFi[2], aFin[2];
  #pragma unroll
  for (int ks = 0; ks < 2; ++ks){
    const int m0 = 2*ks, m1 = 2*ks + 1;
    u32x4 wr4, wi4;
    wr4.x = pack2t(gelu_fast(a1R[m0][0] + br1[m0].x), gelu_fast(a1R[m0][1] + br1[m0].y));
    wr4.y = pack2t(gelu_fast(a1R[m0][2] + br1[m0].z), gelu_fast(a1R[m0][3] + br1[m0].w));
    wr4.z = pack2t(gelu_fast(a1R[m1][0] + br1[m1].x), gelu_fast(a1R[m1][1] + br1[m1].y));
    wr4.w = pack2t(gelu_fast(a1R[m1][2] + br1[m1].z), gelu_fast(a1R[m1][3] + br1[m1].w));
    wi4.x = pack2t(gelu_fast(a1I[m0][0] + bi1[m0].x), gelu_fast(a1I[m0][1] + bi1[m0].y));
    wi4.y = pack2t(gelu_fast(a1I[m0][2] + bi1[m0].z), gelu_fast(a1I[m0][3] + bi1[m0].w));
    wi4.z = pack2t(gelu_fast(a1I[m1][0] + bi1[m1].x), gelu_fast(a1I[m1][1] + bi1[m1].y));
    wi4.w = pack2t(gelu_fast(a1I[m1][2] + bi1[m1].z), gelu_fast(a1I[m1][3] + bi1[m1].w));
    aFr[ks]  = __builtin_bit_cast(bf16x8, wr4);
    aFi[ks]  = __builtin_bit_cast(bf16x8, wi4);
    aFin[ks] = aFi[ks] ^ (short)0x8000;
  }

  // -------- stage 2: O2 = O1 W2 --------
  f32x4 a2R[4], a2I[4];
  #pragma unroll
  for (int nt = 0; nt < 4; ++nt){ a2R[nt] = zz; a2I[nt] = zz; }
  #pragma unroll
  for (int ks = 0; ks < 2; ++ks){
    int b0 = ks*4 + lg;
    #pragma unroll
    for (int nt = 0; nt < 4; ++nt){
      int o2 = nt*16 + lf;
      int swo = (o2 ^ (o2 >> 3)) & 7;
      int off = o2*WP + ((b0 ^ swo) << 3);
      bf16x8 bwr = *(const bf16x8*)(W2R + off);
      bf16x8 bwi = *(const bf16x8*)(W2I + off);
      a2R[nt] = MFMA(aFr[ks],  bwr, a2R[nt]);
      a2R[nt] = MFMA(aFin[ks], bwi, a2R[nt]);
      a2I[nt] = MFMA(aFi[ks],  bwr, a2I[nt]);
      a2I[nt] = MFMA(aFr[ks],  bwi, a2I[nt]);
    }
  }

  // -------- stage-2 epilogue: bias + contiguous 16B tile stores (guarded) --------
  if (tile <= 64){
    unsigned* oblk = spec_out + bhbase + (size_t)tile * 4096;
    int fl0 = wf0 + lg*4;
    #pragma unroll
    for (int nt = 0; nt < 4; ++nt){
      int o2 = nt*16 + lf;
      uint4 st;
      st.x = pack2t(a2R[nt][0] + b2r[nt], a2I[nt][0] + b2i[nt]);
      st.y = pack2t(a2R[nt][1] + b2r[nt], a2I[nt][1] + b2i[nt]);
      st.z = pack2t(a2R[nt][2] + b2r[nt], a2I[nt][2] + b2i[nt]);
      st.w = pack2t(a2R[nt][3] + b2r[nt], a2I[nt][3] + b2i[nt]);
      *(uint4*)(oblk + o2*64 + fl0) = st;
    }
  }
}

// ---------------- launch ----------------
extern "C" void kernel_launch(void* const* d_in, const int* in_sizes, int n_in,
                              void* d_out, int out_size, void* d_ws, size_t ws_size,
                              hipStream_t stream) {
  const float* x  = (const float*)d_in[0];
  const float* w1 = (const float*)d_in[1];
  const float* b1 = (const float*)d_in[2];
  const float* w2 = (const float*)d_in[3];
  const float* b2 = (const float*)d_in[4];
  float* out = (float*)d_out;

  unsigned char* base = (unsigned char*)d_ws;
  if (ws_size < 2 * REGION_BYTES){
    void* p = nullptr;
    hipGetSymbolAddress(&p, HIP_SYMBOL(g_scratch));
    base = (unsigned char*)p;
  }
  unsigned* specA = (unsigned*)base;                 // region A: spectrum1, later yt
  unsigned char* regB = base + REGION_BYTES;         // region B: xt, later spectrum2
  unsigned* xt    = (unsigned*)regB;
  unsigned* specB = (unsigned*)regB;
  unsigned* ytp   = (unsigned*)base;

  // 1) transpose x -> xt (wprep folded into 8 designated blocks)
  transpose_in_k<<<dim3(CC/32, NLEN/64, BB), 256, 0, stream>>>(x, xt, w1, w2);
  // 2) forward rfft -> tile-blocked spectrum (bf16 LDS exchanges)
  fft_fwd_k<<<NSEQ, 256, 0, stream>>>(xt, specA);
  // 3) complex MLP (512 threads, 2 parallel tiles/block, shared W stage)
  afno_mid_mfma_k<<<dim3(33, HH, BB), 512, 0, stream>>>(specA, specB, b1, b2);
  // 4) inverse rfft (bf16 LDS exchanges, folded ortho scale)
  fft_inv_k<<<NSEQ, 256, 0, stream>>>(specB, ytp);
  // 5) transpose yt -> out
  transpose_out_k<<<dim3(CC/32, NLEN/64, BB), 256, 0, stream>>>(ytp, out);
}